// Round 3
// baseline (394.910 us; speedup 1.0000x reference)
//
#include <hip/hip_runtime.h>
#include <cstdint>
#include <cstddef>

typedef float floatx4 __attribute__((ext_vector_type(4)));
typedef _Float16 half8_t __attribute__((ext_vector_type(8)));
typedef _Float16 half2_t __attribute__((ext_vector_type(2)));

#define AS1 __attribute__((address_space(1)))
#define AS3 __attribute__((address_space(3)))

__device__ __forceinline__ void glds16(const void* g, void* l) {
  __builtin_amdgcn_global_load_lds((const AS1 void*)g, (AS3 void*)l, 16, 0, 0);
}

__device__ __forceinline__ half2_t pkrtz(float a, float b) {
  return __builtin_bit_cast(half2_t, __builtin_amdgcn_cvt_pkrtz(a, b));
}

__device__ __forceinline__ float fast_tanh(float x) {
  // tanh(x) = 1 - 2/(e^{2x}+1); inf-safe (e2=inf -> rcp=0 -> 1; e2=0 -> -1)
  float e2 = __expf(2.f * x);
  return 1.f - 2.f * __builtin_amdgcn_rcpf(e2 + 1.f);
}

// ---- K0: Wh (1024x1024 fp32, k-major) -> WhT (n-major, fp16) --------------
__global__ void k0_transpose(const float* __restrict__ Wh, _Float16* __restrict__ WhT) {
  __shared__ float t[64][65];
  int k0 = blockIdx.y << 6, n0 = blockIdx.x << 6;
  int tx = threadIdx.x, ty = threadIdx.y;  // block (64,4)
  #pragma unroll
  for (int r = ty; r < 64; r += 4) t[r][tx] = Wh[(size_t)(k0 + r) * 1024 + n0 + tx];
  __syncthreads();
  #pragma unroll
  for (int r = ty; r < 64; r += 4)
    WhT[(size_t)(n0 + r) * 1024 + k0 + tx] = (_Float16)t[tx][r];
}

// ---- K1: tq = query @ Ws (fp32 vector, 64x1024) ---------------------------
__global__ void k1_tq(const float* __restrict__ q, const float* __restrict__ Ws,
                      float* __restrict__ tq) {
  __shared__ float qs[1024];
  int b = blockIdx.y;
  int d = (blockIdx.x << 8) + threadIdx.x;  // grid.x=4, block=256
  for (int k = threadIdx.x; k < 1024; k += 256) qs[k] = q[(b << 10) + k];
  __syncthreads();
  float acc = 0.f;
  #pragma unroll 8
  for (int k = 0; k < 1024; ++k) acc += qs[k] * Ws[(size_t)k * 1024 + d];
  tq[(b << 10) + d] = acc;
}

// ---- K2: fused GEMM(mem@Wh) + tanh + dot(v) -> logit partials -------------
// A = memory_values (32768x1024 fp32), BT = WhT (1024x1024 fp16, n-major)
// As staged fp32 via global_load_lds with per-row chunk swizzle, cvt->fp16 in reg.
__global__ __launch_bounds__(256, 2) void k2_gemm_logits(
    const float* __restrict__ A, const _Float16* __restrict__ BT,
    const float* __restrict__ tq, const float* __restrict__ v,
    float* __restrict__ partials) {
  __shared__ float As[128 * 32];      // 16 KB, row=128B, swizzled chunks
  __shared__ _Float16 Bs[128 * 32];   // 8 KB,  row=64B,  swizzled chunks
  const int bid = blockIdx.x;
  const int mtile = ((bid >> 6) << 3) | (bid & 7);  // XCD swizzle
  const int nblk = (bid >> 3) & 7;
  const int m0 = mtile << 7, n0 = nblk << 7;
  const int tid = threadIdx.x;
  const int w = tid >> 6, lane = tid & 63;
  const int wm = w >> 1, wn = w & 1, quad = lane >> 4, l15 = lane & 15;

  floatx4 acc[4][4];
  #pragma unroll
  for (int i = 0; i < 4; ++i)
    #pragma unroll
    for (int j = 0; j < 4; ++j) acc[i][j] = floatx4{0.f, 0.f, 0.f, 0.f};

  // A staging: 1024 16B-chunks (4 fp32), 8 per row; LDS pos jj holds global
  // chunk (jj - row) & 7. 4 calls/wave.
  const float* gA[4];
  float* lA[4];
  #pragma unroll
  for (int t = 0; t < 4; ++t) {
    int L = (t << 8) + (w << 6) + lane;
    int row = L >> 3, jj = L & 7;
    int j = (jj - row) & 7;
    gA[t] = A + (size_t)(m0 + row) * 1024 + (j << 2);
    lA[t] = As + (t << 10) + (w << 8);  // wave-uniform base
  }
  // B staging: 512 chunks (8 fp16), 4 per row; pos jj holds (jj - row - row/4)&3.
  const _Float16* gB[2];
  _Float16* lB[2];
  #pragma unroll
  for (int t = 0; t < 2; ++t) {
    int L = (t << 8) + (w << 6) + lane;
    int row = L >> 2, jj = L & 3;
    int j = (jj - row - (row >> 2)) & 3;
    gB[t] = BT + (size_t)(n0 + row) * 1024 + (j << 3);
    lB[t] = Bs + (t << 11) + (w << 9);
  }

  // fragment LDS addresses (loop-invariant)
  const floatx4* aaddr[4][2];
  #pragma unroll
  for (int i = 0; i < 4; ++i) {
    int row = (wm << 6) + (i << 4) + l15;
    #pragma unroll
    for (int h = 0; h < 2; ++h) {
      int pos = ((quad << 1) + h + row) & 7;
      aaddr[i][h] = (const floatx4*)(As + (row << 5) + (pos << 2));
    }
  }
  const half8_t* baddr[4];
  #pragma unroll
  for (int j = 0; j < 4; ++j) {
    int row = (wn << 6) + (j << 4) + l15;
    int pos = (quad + row + (row >> 2)) & 3;
    baddr[j] = (const half8_t*)(Bs + (row << 5) + (pos << 3));
  }

  for (int k0 = 0; k0 < 1024; k0 += 32) {
    __syncthreads();
    glds16(gA[0] + k0, lA[0]);
    glds16(gA[1] + k0, lA[1]);
    glds16(gA[2] + k0, lA[2]);
    glds16(gA[3] + k0, lA[3]);
    glds16(gB[0] + k0, lB[0]);
    glds16(gB[1] + k0, lB[1]);
    __syncthreads();
    half8_t af[4], bfr[4];
    #pragma unroll
    for (int i = 0; i < 4; ++i) {
      floatx4 x = *aaddr[i][0], y = *aaddr[i][1];
      union { half2_t h2[4]; half8_t h8; } u;
      u.h2[0] = pkrtz(x[0], x[1]);
      u.h2[1] = pkrtz(x[2], x[3]);
      u.h2[2] = pkrtz(y[0], y[1]);
      u.h2[3] = pkrtz(y[2], y[3]);
      af[i] = u.h8;
    }
    #pragma unroll
    for (int j = 0; j < 4; ++j) bfr[j] = *baddr[j];
    #pragma unroll
    for (int i = 0; i < 4; ++i)
      #pragma unroll
      for (int j = 0; j < 4; ++j)
        acc[i][j] = __builtin_amdgcn_mfma_f32_16x16x32_f16(af[i], bfr[j], acc[i][j], 0, 0, 0);
  }

  // epilogue: tanh(C + tq[b][n]) * v[n], reduce over this wave's 64 cols
  const int b = m0 >> 9;  // 128-row tiles never cross batch boundary
  const int colbase = n0 + (wn << 6) + l15;
  float tqv[4], vv[4];
  #pragma unroll
  for (int j = 0; j < 4; ++j) {
    int n = colbase + (j << 4);
    tqv[j] = tq[(b << 10) + n];
    vv[j] = v[n];
  }
  #pragma unroll
  for (int i = 0; i < 4; ++i) {
    #pragma unroll
    for (int r = 0; r < 4; ++r) {
      float s = 0.f;
      #pragma unroll
      for (int j = 0; j < 4; ++j) s += fast_tanh(acc[i][j][r] + tqv[j]) * vv[j];
      s += __shfl_xor(s, 1);
      s += __shfl_xor(s, 2);
      s += __shfl_xor(s, 4);
      s += __shfl_xor(s, 8);
      if (l15 == 0) {
        int m = m0 + (wm << 6) + (i << 4) + (quad << 2) + r;
        partials[m * 16 + (nblk << 1) + wn] = s;
      }
    }
  }
}

// ---- K3: masked softmax over N=512 per batch ------------------------------
__global__ __launch_bounds__(512) void k3_softmax(const float* __restrict__ partials,
                                                  const int* __restrict__ mask,
                                                  float* __restrict__ weights) {
  int b = blockIdx.x;
  int n = threadIdx.x;  // 512
  int m = (b << 9) + n;
  float s = 0.f;
  #pragma unroll
  for (int i = 0; i < 16; ++i) s += partials[m * 16 + i];
  int mk = mask[m];
  float logit = mk ? s : -1e30f;
  __shared__ float red[8];
  float x = logit;
  #pragma unroll
  for (int off = 32; off > 0; off >>= 1) x = fmaxf(x, __shfl_xor(x, off));
  if ((n & 63) == 0) red[n >> 6] = x;
  __syncthreads();
  float mx = red[0];
  #pragma unroll
  for (int i = 1; i < 8; ++i) mx = fmaxf(mx, red[i]);
  float e = mk ? __expf(logit - mx) : 0.f;
  float ss = e;
  #pragma unroll
  for (int off = 32; off > 0; off >>= 1) ss += __shfl_xor(ss, off);
  __syncthreads();
  if ((n & 63) == 0) red[n >> 6] = ss;
  __syncthreads();
  float tot = 0.f;
  #pragma unroll
  for (int i = 0; i < 8; ++i) tot += red[i];
  weights[m] = (tot > 0.f) ? e / tot : 0.f;
}

// ---- K4: context partials over 64-row n-chunks (fp32 mem) -----------------
__global__ void k4_ctx(const float* __restrict__ mem, const float* __restrict__ weights,
                       float* __restrict__ ctxp) {
  int nc = blockIdx.x;  // 8 chunks
  int b = blockIdx.y;
  int d = threadIdx.x << 3;  // 128 threads x 8 = 1024
  floatx4 a0 = {0.f, 0.f, 0.f, 0.f}, a1 = {0.f, 0.f, 0.f, 0.f};
  int nbase = nc << 6;
  for (int n = nbase; n < nbase + 64; ++n) {
    float wv = weights[(b << 9) + n];
    const floatx4* p = (const floatx4*)(mem + ((size_t)((b << 9) + n) << 10) + d);
    a0 += wv * p[0];
    a1 += wv * p[1];
  }
  floatx4* o = (floatx4*)(ctxp + ((size_t)((b << 3) + nc) << 10) + d);
  o[0] = a0;
  o[1] = a1;
}

// ---- K5: reduce 8 context partials (fp32 out) -----------------------------
__global__ void k5_reduce(const float* __restrict__ ctxp, float* __restrict__ out) {
  int i = (blockIdx.x << 8) + threadIdx.x;  // 65536
  int b = i >> 10, d = i & 1023;
  float s = 0.f;
  #pragma unroll
  for (int cc = 0; cc < 8; ++cc) s += ctxp[((size_t)((b << 3) + cc) << 10) + d];
  out[i] = s;
}

extern "C" void kernel_launch(void* const* d_in, const int* in_sizes, int n_in,
                              void* d_out, int out_size, void* d_ws, size_t ws_size,
                              hipStream_t stream) {
  const float* mem = (const float*)d_in[0];   // (64,512,1024) fp32
  const int* mask = (const int*)d_in[1];      // (64,512) int32
  const float* query = (const float*)d_in[2]; // (64,1024) fp32
  const float* Wh = (const float*)d_in[3];    // (1024,1024) fp32
  const float* Ws = (const float*)d_in[4];    // (1024,1024) fp32
  const float* v = (const float*)d_in[5];     // (1024,1) fp32
  float* out = (float*)d_out;                 // (64,1024) fp32

  char* ws = (char*)d_ws;
  _Float16* WhT = (_Float16*)ws;                                   // 2 MiB
  float* partials = (float*)(ws + ((size_t)2 << 20));              // 2 MiB
  float* tq = (float*)(ws + ((size_t)4 << 20));                    // 256 KiB
  float* weights = (float*)(ws + ((size_t)4 << 20) + (256 << 10)); // 128 KiB
  float* ctxp = (float*)(ws + ((size_t)9 << 19));                  // 2 MiB @4.5M

  k0_transpose<<<dim3(16, 16), dim3(64, 4), 0, stream>>>(Wh, WhT);
  k1_tq<<<dim3(4, 64), 256, 0, stream>>>(query, Ws, tq);
  k2_gemm_logits<<<2048, 256, 0, stream>>>(mem, WhT, tq, v, partials);
  k3_softmax<<<64, 512, 0, stream>>>(partials, mask, weights);
  k4_ctx<<<dim3(8, 64), 128, 0, stream>>>(mem, weights, ctxp);
  k5_reduce<<<256, 256, 0, stream>>>(ctxp, out);
}

// Round 4
// 333.822 us; speedup vs baseline: 1.1830x; 1.1830x over previous
//
#include <hip/hip_runtime.h>
#include <cstdint>
#include <cstddef>

typedef float floatx4 __attribute__((ext_vector_type(4)));
typedef _Float16 half8_t __attribute__((ext_vector_type(8)));
typedef _Float16 half2_t __attribute__((ext_vector_type(2)));

#define AS1 __attribute__((address_space(1)))
#define AS3 __attribute__((address_space(3)))

__device__ __forceinline__ void glds16(const void* g, void* l) {
  __builtin_amdgcn_global_load_lds((const AS1 void*)g, (AS3 void*)l, 16, 0, 0);
}

__device__ __forceinline__ half2_t pkrtz(float a, float b) {
  return __builtin_bit_cast(half2_t, __builtin_amdgcn_cvt_pkrtz(a, b));
}

__device__ __forceinline__ float fast_tanh(float x) {
  // tanh(x) = 1 - 2/(e^{2x}+1); inf-safe (e2=inf -> rcp=0 -> 1; e2=0 -> -1)
  float e2 = __expf(2.f * x);
  return 1.f - 2.f * __builtin_amdgcn_rcpf(e2 + 1.f);
}

// ---- Kpre: memory_values fp32 -> fp16 copy (33.5M elems, 8 per thread) ----
__global__ void kp_cvt(const float* __restrict__ mem, _Float16* __restrict__ memh) {
  size_t i = ((size_t)(blockIdx.x << 8) + threadIdx.x) << 3;
  floatx4 a = *(const floatx4*)(mem + i);
  floatx4 b = *(const floatx4*)(mem + i + 4);
  union { half2_t h2[4]; half8_t h8; } u;
  u.h2[0] = half2_t{(_Float16)a[0], (_Float16)a[1]};
  u.h2[1] = half2_t{(_Float16)a[2], (_Float16)a[3]};
  u.h2[2] = half2_t{(_Float16)b[0], (_Float16)b[1]};
  u.h2[3] = half2_t{(_Float16)b[2], (_Float16)b[3]};
  *(half8_t*)(memh + i) = u.h8;
}

// ---- K0: Wh (1024x1024 fp32, k-major) -> WhT (n-major, fp16) --------------
__global__ void k0_transpose(const float* __restrict__ Wh, _Float16* __restrict__ WhT) {
  __shared__ float t[64][65];
  int k0 = blockIdx.y << 6, n0 = blockIdx.x << 6;
  int tx = threadIdx.x, ty = threadIdx.y;  // block (64,4)
  #pragma unroll
  for (int r = ty; r < 64; r += 4) t[r][tx] = Wh[(size_t)(k0 + r) * 1024 + n0 + tx];
  __syncthreads();
  #pragma unroll
  for (int r = ty; r < 64; r += 4)
    WhT[(size_t)(n0 + r) * 1024 + k0 + tx] = (_Float16)t[tx][r];
}

// ---- K1: tq = query @ Ws, K-split 4-way, grid (16 dchunk, 64 b) -----------
__global__ __launch_bounds__(256) void k1_tq(const float* __restrict__ q,
                                             const float* __restrict__ Ws,
                                             float* __restrict__ tq) {
  __shared__ float qs[1024];
  __shared__ float red[4][64];
  int b = blockIdx.y;
  int d0 = blockIdx.x << 6;
  int dl = threadIdx.x & 63, kg = threadIdx.x >> 6;
  for (int k = threadIdx.x; k < 1024; k += 256) qs[k] = q[(b << 10) + k];
  __syncthreads();
  float acc = 0.f;
  int kbase = kg << 8;
  #pragma unroll 8
  for (int k = 0; k < 256; ++k)
    acc += qs[kbase + k] * Ws[(size_t)(kbase + k) * 1024 + d0 + dl];
  red[kg][dl] = acc;
  __syncthreads();
  if (kg == 0)
    tq[(b << 10) + d0 + dl] = red[0][dl] + red[1][dl] + red[2][dl] + red[3][dl];
}

// ---- K2 (fp16 path): m97-structure GEMM + tanh + dot(v) -> partials -------
// Ah = memory_values fp16 (32768x1024), BT = WhT fp16 (1024x1024, n-major)
// LDS rows 64B = 4 chunks of 16B; chunk j of row r stored at pos (j+r+(r>>2))&3.
__global__ __launch_bounds__(256, 2) void k2_gemm_h(
    const _Float16* __restrict__ Ah, const _Float16* __restrict__ BT,
    const float* __restrict__ tq, const float* __restrict__ v,
    float* __restrict__ partials) {
  __shared__ _Float16 As[128 * 32];  // 8 KB
  __shared__ _Float16 Bs[128 * 32];  // 8 KB
  const int bid = blockIdx.x;
  const int mtile = ((bid >> 6) << 3) | (bid & 7);  // XCD swizzle
  const int nblk = (bid >> 3) & 7;
  const int m0 = mtile << 7, n0 = nblk << 7;
  const int tid = threadIdx.x;
  const int w = tid >> 6, lane = tid & 63;
  const int wm = w >> 1, wn = w & 1, quad = lane >> 4, l15 = lane & 15;

  floatx4 acc[4][4];
  #pragma unroll
  for (int i = 0; i < 4; ++i)
    #pragma unroll
    for (int j = 0; j < 4; ++j) acc[i][j] = floatx4{0.f, 0.f, 0.f, 0.f};

  const _Float16 *gA[2], *gB[2];
  _Float16 *lA[2], *lB[2];
  #pragma unroll
  for (int t = 0; t < 2; ++t) {
    int L = (t << 8) + (w << 6) + lane;
    int row = L >> 2, jj = L & 3;
    int j = (jj - row - (row >> 2)) & 3;  // global chunk stored at LDS pos jj
    gA[t] = Ah + (size_t)(m0 + row) * 1024 + (j << 3);
    gB[t] = BT + (size_t)(n0 + row) * 1024 + (j << 3);
    lA[t] = As + (t << 11) + (w << 9);  // wave-uniform base
    lB[t] = Bs + (t << 11) + (w << 9);
  }

  const half8_t *aaddr[4], *baddr[4];
  #pragma unroll
  for (int i = 0; i < 4; ++i) {
    int ar = (wm << 6) + (i << 4) + l15;
    aaddr[i] = (const half8_t*)(As + (ar << 5) + (((quad + ar + (ar >> 2)) & 3) << 3));
    int br = (wn << 6) + (i << 4) + l15;
    baddr[i] = (const half8_t*)(Bs + (br << 5) + (((quad + br + (br >> 2)) & 3) << 3));
  }

  for (int k0 = 0; k0 < 1024; k0 += 32) {
    __syncthreads();
    glds16(gA[0] + k0, lA[0]);
    glds16(gA[1] + k0, lA[1]);
    glds16(gB[0] + k0, lB[0]);
    glds16(gB[1] + k0, lB[1]);
    __syncthreads();
    half8_t af[4], bfr[4];
    #pragma unroll
    for (int i = 0; i < 4; ++i) af[i] = *aaddr[i];
    #pragma unroll
    for (int j = 0; j < 4; ++j) bfr[j] = *baddr[j];
    #pragma unroll
    for (int i = 0; i < 4; ++i)
      #pragma unroll
      for (int j = 0; j < 4; ++j)
        acc[i][j] = __builtin_amdgcn_mfma_f32_16x16x32_f16(af[i], bfr[j], acc[i][j], 0, 0, 0);
  }

  const int b = m0 >> 9;
  const int colbase = n0 + (wn << 6) + l15;
  float tqv[4], vv[4];
  #pragma unroll
  for (int j = 0; j < 4; ++j) {
    int n = colbase + (j << 4);
    tqv[j] = tq[(b << 10) + n];
    vv[j] = v[n];
  }
  #pragma unroll
  for (int i = 0; i < 4; ++i) {
    #pragma unroll
    for (int r = 0; r < 4; ++r) {
      float s = 0.f;
      #pragma unroll
      for (int j = 0; j < 4; ++j) s += fast_tanh(acc[i][j][r] + tqv[j]) * vv[j];
      s += __shfl_xor(s, 1);
      s += __shfl_xor(s, 2);
      s += __shfl_xor(s, 4);
      s += __shfl_xor(s, 8);
      if (l15 == 0) {
        int m = m0 + (wm << 6) + (i << 4) + (quad << 2) + r;
        partials[m * 16 + (nblk << 1) + wn] = s;
      }
    }
  }
}

// ---- K2 fallback (fp32 A staging) — round-3 verified path -----------------
__global__ __launch_bounds__(256, 2) void k2_gemm_f32(
    const float* __restrict__ A, const _Float16* __restrict__ BT,
    const float* __restrict__ tq, const float* __restrict__ v,
    float* __restrict__ partials) {
  __shared__ float As[128 * 32];
  __shared__ _Float16 Bs[128 * 32];
  const int bid = blockIdx.x;
  const int mtile = ((bid >> 6) << 3) | (bid & 7);
  const int nblk = (bid >> 3) & 7;
  const int m0 = mtile << 7, n0 = nblk << 7;
  const int tid = threadIdx.x;
  const int w = tid >> 6, lane = tid & 63;
  const int wm = w >> 1, wn = w & 1, quad = lane >> 4, l15 = lane & 15;

  floatx4 acc[4][4];
  #pragma unroll
  for (int i = 0; i < 4; ++i)
    #pragma unroll
    for (int j = 0; j < 4; ++j) acc[i][j] = floatx4{0.f, 0.f, 0.f, 0.f};

  const float* gA[4];
  float* lA[4];
  #pragma unroll
  for (int t = 0; t < 4; ++t) {
    int L = (t << 8) + (w << 6) + lane;
    int row = L >> 3, jj = L & 7;
    int j = (jj - row) & 7;
    gA[t] = A + (size_t)(m0 + row) * 1024 + (j << 2);
    lA[t] = As + (t << 10) + (w << 8);
  }
  const _Float16* gB[2];
  _Float16* lB[2];
  #pragma unroll
  for (int t = 0; t < 2; ++t) {
    int L = (t << 8) + (w << 6) + lane;
    int row = L >> 2, jj = L & 3;
    int j = (jj - row - (row >> 2)) & 3;
    gB[t] = BT + (size_t)(n0 + row) * 1024 + (j << 3);
    lB[t] = Bs + (t << 11) + (w << 9);
  }
  const floatx4* aaddr[4][2];
  #pragma unroll
  for (int i = 0; i < 4; ++i) {
    int row = (wm << 6) + (i << 4) + l15;
    #pragma unroll
    for (int h = 0; h < 2; ++h) {
      int pos = ((quad << 1) + h + row) & 7;
      aaddr[i][h] = (const floatx4*)(As + (row << 5) + (pos << 2));
    }
  }
  const half8_t* baddr[4];
  #pragma unroll
  for (int j = 0; j < 4; ++j) {
    int row = (wn << 6) + (j << 4) + l15;
    int pos = (quad + row + (row >> 2)) & 3;
    baddr[j] = (const half8_t*)(Bs + (row << 5) + (pos << 3));
  }
  for (int k0 = 0; k0 < 1024; k0 += 32) {
    __syncthreads();
    glds16(gA[0] + k0, lA[0]);
    glds16(gA[1] + k0, lA[1]);
    glds16(gA[2] + k0, lA[2]);
    glds16(gA[3] + k0, lA[3]);
    glds16(gB[0] + k0, lB[0]);
    glds16(gB[1] + k0, lB[1]);
    __syncthreads();
    half8_t af[4], bfr[4];
    #pragma unroll
    for (int i = 0; i < 4; ++i) {
      floatx4 x = *aaddr[i][0], y = *aaddr[i][1];
      union { half2_t h2[4]; half8_t h8; } u;
      u.h2[0] = pkrtz(x[0], x[1]);
      u.h2[1] = pkrtz(x[2], x[3]);
      u.h2[2] = pkrtz(y[0], y[1]);
      u.h2[3] = pkrtz(y[2], y[3]);
      af[i] = u.h8;
    }
    #pragma unroll
    for (int j = 0; j < 4; ++j) bfr[j] = *baddr[j];
    #pragma unroll
    for (int i = 0; i < 4; ++i)
      #pragma unroll
      for (int j = 0; j < 4; ++j)
        acc[i][j] = __builtin_amdgcn_mfma_f32_16x16x32_f16(af[i], bfr[j], acc[i][j], 0, 0, 0);
  }
  const int b = m0 >> 9;
  const int colbase = n0 + (wn << 6) + l15;
  float tqv[4], vv[4];
  #pragma unroll
  for (int j = 0; j < 4; ++j) {
    int n = colbase + (j << 4);
    tqv[j] = tq[(b << 10) + n];
    vv[j] = v[n];
  }
  #pragma unroll
  for (int i = 0; i < 4; ++i) {
    #pragma unroll
    for (int r = 0; r < 4; ++r) {
      float s = 0.f;
      #pragma unroll
      for (int j = 0; j < 4; ++j) s += fast_tanh(acc[i][j][r] + tqv[j]) * vv[j];
      s += __shfl_xor(s, 1);
      s += __shfl_xor(s, 2);
      s += __shfl_xor(s, 4);
      s += __shfl_xor(s, 8);
      if (l15 == 0) {
        int m = m0 + (wm << 6) + (i << 4) + (quad << 2) + r;
        partials[m * 16 + (nblk << 1) + wn] = s;
      }
    }
  }
}

// ---- K3: masked softmax over N=512 per batch ------------------------------
__global__ __launch_bounds__(512) void k3_softmax(const float* __restrict__ partials,
                                                  const int* __restrict__ mask,
                                                  float* __restrict__ weights) {
  int b = blockIdx.x;
  int n = threadIdx.x;
  int m = (b << 9) + n;
  float s = 0.f;
  #pragma unroll
  for (int i = 0; i < 16; ++i) s += partials[m * 16 + i];
  int mk = mask[m];
  float logit = mk ? s : -1e30f;
  __shared__ float red[8];
  float x = logit;
  #pragma unroll
  for (int off = 32; off > 0; off >>= 1) x = fmaxf(x, __shfl_xor(x, off));
  if ((n & 63) == 0) red[n >> 6] = x;
  __syncthreads();
  float mx = red[0];
  #pragma unroll
  for (int i = 1; i < 8; ++i) mx = fmaxf(mx, red[i]);
  float e = mk ? __expf(logit - mx) : 0.f;
  float ss = e;
  #pragma unroll
  for (int off = 32; off > 0; off >>= 1) ss += __shfl_xor(ss, off);
  __syncthreads();
  if ((n & 63) == 0) red[n >> 6] = ss;
  __syncthreads();
  float tot = 0.f;
  #pragma unroll
  for (int i = 0; i < 8; ++i) tot += red[i];
  weights[m] = (tot > 0.f) ? e / tot : 0.f;
}

// ---- K4 (fp16 mem): context partials over 32-row chunks, grid (16,64) -----
__global__ void k4_ctx_h(const _Float16* __restrict__ memh,
                         const float* __restrict__ weights, float* __restrict__ ctxp) {
  int nc = blockIdx.x, b = blockIdx.y;
  int d = threadIdx.x << 3;  // 128 threads x 8 cols
  float acc[8] = {0.f, 0.f, 0.f, 0.f, 0.f, 0.f, 0.f, 0.f};
  int nbase = nc << 5;
  for (int n = nbase; n < nbase + 32; ++n) {
    float wv = weights[(b << 9) + n];
    half8_t x = *(const half8_t*)(memh + ((size_t)((b << 9) + n) << 10) + d);
    #pragma unroll
    for (int k = 0; k < 8; ++k) acc[k] += wv * (float)x[k];
  }
  float* o = ctxp + ((size_t)((b << 4) + nc) << 10) + d;
  #pragma unroll
  for (int k = 0; k < 8; ++k) o[k] = acc[k];
}

__global__ void k5_reduce16(const float* __restrict__ ctxp, float* __restrict__ out) {
  int i = (blockIdx.x << 8) + threadIdx.x;
  int b = i >> 10, d = i & 1023;
  float s = 0.f;
  #pragma unroll
  for (int cc = 0; cc < 16; ++cc) s += ctxp[((size_t)((b << 4) + cc) << 10) + d];
  out[i] = s;
}

// ---- fp32-path K4/K5 (round-3 verified) -----------------------------------
__global__ void k4_ctx_f32(const float* __restrict__ mem, const float* __restrict__ weights,
                           float* __restrict__ ctxp) {
  int nc = blockIdx.x, b = blockIdx.y;
  int d = threadIdx.x << 3;
  floatx4 a0 = {0.f, 0.f, 0.f, 0.f}, a1 = {0.f, 0.f, 0.f, 0.f};
  int nbase = nc << 6;
  for (int n = nbase; n < nbase + 64; ++n) {
    float wv = weights[(b << 9) + n];
    const floatx4* p = (const floatx4*)(mem + ((size_t)((b << 9) + n) << 10) + d);
    a0 += wv * p[0];
    a1 += wv * p[1];
  }
  floatx4* o = (floatx4*)(ctxp + ((size_t)((b << 3) + nc) << 10) + d);
  o[0] = a0;
  o[1] = a1;
}

__global__ void k5_reduce8(const float* __restrict__ ctxp, float* __restrict__ out) {
  int i = (blockIdx.x << 8) + threadIdx.x;
  int b = i >> 10, d = i & 1023;
  float s = 0.f;
  #pragma unroll
  for (int cc = 0; cc < 8; ++cc) s += ctxp[((size_t)((b << 3) + cc) << 10) + d];
  out[i] = s;
}

extern "C" void kernel_launch(void* const* d_in, const int* in_sizes, int n_in,
                              void* d_out, int out_size, void* d_ws, size_t ws_size,
                              hipStream_t stream) {
  const float* mem = (const float*)d_in[0];   // (64,512,1024) fp32
  const int* mask = (const int*)d_in[1];      // (64,512) int32
  const float* query = (const float*)d_in[2]; // (64,1024) fp32
  const float* Wh = (const float*)d_in[3];    // (1024,1024) fp32
  const float* Ws = (const float*)d_in[4];    // (1024,1024) fp32
  const float* v = (const float*)d_in[5];     // (1024,1) fp32
  float* out = (float*)d_out;                 // (64,1024) fp32

  char* ws = (char*)d_ws;
  const size_t need16 = (73ull << 20);

  if (ws_size >= need16) {
    _Float16* memh = (_Float16*)ws;                                    // 64 MiB
    _Float16* WhT = (_Float16*)(ws + (64ull << 20));                   // 2 MiB
    float* partials = (float*)(ws + (66ull << 20));                    // 2 MiB
    float* tq = (float*)(ws + (68ull << 20));                          // 256 KiB
    float* weights = (float*)(ws + (68ull << 20) + (256 << 10));       // 128 KiB
    float* ctxp = (float*)(ws + (69ull << 20));                        // 4 MiB

    kp_cvt<<<16384, 256, 0, stream>>>(mem, memh);
    k0_transpose<<<dim3(16, 16), dim3(64, 4), 0, stream>>>(Wh, WhT);
    k1_tq<<<dim3(16, 64), 256, 0, stream>>>(query, Ws, tq);
    k2_gemm_h<<<2048, 256, 0, stream>>>(memh, WhT, tq, v, partials);
    k3_softmax<<<64, 512, 0, stream>>>(partials, mask, weights);
    k4_ctx_h<<<dim3(16, 64), 128, 0, stream>>>(memh, weights, ctxp);
    k5_reduce16<<<256, 256, 0, stream>>>(ctxp, out);
  } else {
    _Float16* WhT = (_Float16*)ws;                                     // 2 MiB
    float* partials = (float*)(ws + ((size_t)2 << 20));                // 2 MiB
    float* tq = (float*)(ws + ((size_t)4 << 20));                      // 256 KiB
    float* weights = (float*)(ws + ((size_t)4 << 20) + (256 << 10));   // 128 KiB
    float* ctxp = (float*)(ws + ((size_t)9 << 19));                    // 2 MiB

    k0_transpose<<<dim3(16, 16), dim3(64, 4), 0, stream>>>(Wh, WhT);
    k1_tq<<<dim3(16, 64), 256, 0, stream>>>(query, Ws, tq);
    k2_gemm_f32<<<2048, 256, 0, stream>>>(mem, WhT, tq, v, partials);
    k3_softmax<<<64, 512, 0, stream>>>(partials, mask, weights);
    k4_ctx_f32<<<dim3(8, 64), 128, 0, stream>>>(mem, weights, ctxp);
    k5_reduce8<<<256, 256, 0, stream>>>(ctxp, out);
  }
}